// Round 1
// baseline (6065.241 us; speedup 1.0000x reference)
//
#include <hip/hip_runtime.h>

#define NN 50000
#define NE 800000

__device__ __forceinline__ float silu_f(float v) { return v / (1.f + __expf(-v)); }

// ---------------------------------------------------------------- embed + x copy
__global__ __launch_bounds__(256) void k_embed(
    const float* __restrict__ h_in, const float* __restrict__ x_in,
    const float* __restrict__ W, const float* __restrict__ b,
    float* __restrict__ h, float* __restrict__ x)
{
    int t = blockIdx.x * 256 + threadIdx.x;     // grid exactly NN*64 = 3.2M
    if (t < NN * 3) x[t] = x_in[t];
    int n = t >> 6, j = t & 63;
    const float* hr = h_in + n * 16;
    float acc = b[j];
#pragma unroll
    for (int k = 0; k < 16; k++) acc = fmaf(hr[k], W[k * 64 + j], acc);
    h[t] = acc;
}

// ------------------------------------------- per-node P = h@Wa + be1, Q = h@Wb; zero agg/dx
__global__ __launch_bounds__(256) void k_pq(
    const float* __restrict__ h, const float* __restrict__ We1, const float* __restrict__ be1,
    float* __restrict__ P, float* __restrict__ Q,
    float* __restrict__ agg, float* __restrict__ dxb)
{
    __shared__ float sWa[4096], sWb[4096];
    for (int i = threadIdx.x; i < 4096; i += 256) { sWa[i] = We1[i]; sWb[i] = We1[4096 + i]; }
    __syncthreads();
    int t = blockIdx.x * 256 + threadIdx.x;     // grid exactly NN*64
    int n = t >> 6, j = t & 63;
    const float4* hr = reinterpret_cast<const float4*>(h + n * 64);
    float a = be1[j], bacc = 0.f;
#pragma unroll
    for (int kb = 0; kb < 16; kb++) {
        float4 hv = hr[kb];
        a = fmaf(hv.x, sWa[(4 * kb + 0) * 64 + j], a); bacc = fmaf(hv.x, sWb[(4 * kb + 0) * 64 + j], bacc);
        a = fmaf(hv.y, sWa[(4 * kb + 1) * 64 + j], a); bacc = fmaf(hv.y, sWb[(4 * kb + 1) * 64 + j], bacc);
        a = fmaf(hv.z, sWa[(4 * kb + 2) * 64 + j], a); bacc = fmaf(hv.z, sWb[(4 * kb + 2) * 64 + j], bacc);
        a = fmaf(hv.w, sWa[(4 * kb + 3) * 64 + j], a); bacc = fmaf(hv.w, sWb[(4 * kb + 3) * 64 + j], bacc);
    }
    P[t] = a; Q[t] = bacc;
    agg[t] = 0.f;
    if (t < NN * 3) dxb[t] = 0.f;
}

// ---------------------------------------------------------------- edge kernel
// wave handles 8 edges: m1 = silu(P[src]+Q[dst]+d2*wd); m = silu(m1@We2+be2);
// atomic scatter agg[dst] += m, dx[dst] += rel * (m.Wx)
__global__ __launch_bounds__(256) void k_edge(
    const int* __restrict__ src, const int* __restrict__ dst,
    const float* __restrict__ x,
    const float* __restrict__ P, const float* __restrict__ Q,
    const float* __restrict__ Wd,      // We1 row 128 (64 floats)
    const float* __restrict__ We2, const float* __restrict__ be2,
    const float* __restrict__ Wx,
    float* __restrict__ agg, float* __restrict__ dxb)
{
    __shared__ float sW[4096];                       // We2
    __shared__ __align__(16) float sm1[4][8][64];    // per-wave m1 tiles
    for (int i = threadIdx.x; i < 4096; i += 256) sW[i] = We2[i];
    int wv = threadIdx.x >> 6, j = threadIdx.x & 63;
    int base = (blockIdx.x * 4 + wv) * 8;            // E = 800000 = 25000*32, exact

    int4 sv0 = *reinterpret_cast<const int4*>(src + base);
    int4 sv1 = *reinterpret_cast<const int4*>(src + base + 4);
    int4 dv0 = *reinterpret_cast<const int4*>(dst + base);
    int4 dv1 = *reinterpret_cast<const int4*>(dst + base + 4);
    int s[8] = { sv0.x, sv0.y, sv0.z, sv0.w, sv1.x, sv1.y, sv1.z, sv1.w };
    int d[8] = { dv0.x, dv0.y, dv0.z, dv0.w, dv1.x, dv1.y, dv1.z, dv1.w };

    float relx[8], rely[8], relz[8];
#pragma unroll
    for (int r = 0; r < 8; r++) {
        float ax = x[3 * s[r]], ay = x[3 * s[r] + 1], az = x[3 * s[r] + 2];
        float bx = x[3 * d[r]], by = x[3 * d[r] + 1], bz = x[3 * d[r] + 2];
        relx[r] = ax - bx; rely[r] = ay - by; relz[r] = az - bz;
    }
    float wd = Wd[j];
#pragma unroll
    for (int r = 0; r < 8; r++) {
        float d2 = relx[r] * relx[r] + rely[r] * rely[r] + relz[r] * relz[r];
        float v = P[s[r] * 64 + j] + Q[d[r] * 64 + j] + d2 * wd;   // be1 folded into P
        sm1[wv][r][j] = silu_f(v);
    }
    __syncthreads();

    float acc[8];
    float b2 = be2[j];
#pragma unroll
    for (int r = 0; r < 8; r++) acc[r] = b2;
    for (int kb = 0; kb < 16; kb++) {
        float w0 = sW[(4 * kb + 0) * 64 + j], w1 = sW[(4 * kb + 1) * 64 + j];
        float w2 = sW[(4 * kb + 2) * 64 + j], w3 = sW[(4 * kb + 3) * 64 + j];
#pragma unroll
        for (int r = 0; r < 8; r++) {
            float4 m = *reinterpret_cast<const float4*>(&sm1[wv][r][4 * kb]);
            acc[r] += m.x * w0 + m.y * w1 + m.z * w2 + m.w * w3;
        }
    }
    float wxj = Wx[j];
#pragma unroll
    for (int r = 0; r < 8; r++) {
        float mval = silu_f(acc[r]);
        unsafeAtomicAdd(&agg[d[r] * 64 + j], mval);
        float p = mval * wxj;
        p += __shfl_xor(p, 32); p += __shfl_xor(p, 16); p += __shfl_xor(p, 8);
        p += __shfl_xor(p, 4);  p += __shfl_xor(p, 2);  p += __shfl_xor(p, 1);
        if (j < 3) {
            float rc = (j == 0) ? relx[r] : ((j == 1) ? rely[r] : relz[r]);
            unsafeAtomicAdd(&dxb[d[r] * 3 + j], rc * p);
        }
    }
}

// ---------------------------------------------------------------- node update
__global__ __launch_bounds__(256) void k_node(
    float* __restrict__ h, float* __restrict__ x,
    const float* __restrict__ agg, const float* __restrict__ dxb,
    const float* __restrict__ Wn1, const float* __restrict__ bn1,
    const float* __restrict__ Wn2, const float* __restrict__ bn2)
{
    __shared__ float sW1[8192];
    __shared__ float sW2[4096];
    __shared__ __align__(16) float sh[4][8][64];
    __shared__ __align__(16) float sa[4][8][64];
    __shared__ __align__(16) float su[4][8][64];
    for (int i = threadIdx.x; i < 8192; i += 256) sW1[i] = Wn1[i];
    for (int i = threadIdx.x; i < 4096; i += 256) sW2[i] = Wn2[i];
    int wv = threadIdx.x >> 6, j = threadIdx.x & 63;
    int base = (blockIdx.x * 4 + wv) * 8;
#pragma unroll
    for (int r = 0; r < 8; r++) {
        int n = base + r;
        sh[wv][r][j] = (n < NN) ? h[n * 64 + j] : 0.f;
        sa[wv][r][j] = (n < NN) ? agg[n * 64 + j] : 0.f;
    }
    __syncthreads();

    float acc[8];
    float b1 = bn1[j];
#pragma unroll
    for (int r = 0; r < 8; r++) acc[r] = b1;
    for (int kb = 0; kb < 16; kb++) {
        float w0 = sW1[(4 * kb + 0) * 64 + j], w1 = sW1[(4 * kb + 1) * 64 + j];
        float w2 = sW1[(4 * kb + 2) * 64 + j], w3 = sW1[(4 * kb + 3) * 64 + j];
#pragma unroll
        for (int r = 0; r < 8; r++) {
            float4 m = *reinterpret_cast<const float4*>(&sh[wv][r][4 * kb]);
            acc[r] += m.x * w0 + m.y * w1 + m.z * w2 + m.w * w3;
        }
    }
    for (int kb = 0; kb < 16; kb++) {
        float w0 = sW1[(64 + 4 * kb + 0) * 64 + j], w1 = sW1[(64 + 4 * kb + 1) * 64 + j];
        float w2 = sW1[(64 + 4 * kb + 2) * 64 + j], w3 = sW1[(64 + 4 * kb + 3) * 64 + j];
#pragma unroll
        for (int r = 0; r < 8; r++) {
            float4 m = *reinterpret_cast<const float4*>(&sa[wv][r][4 * kb]);
            acc[r] += m.x * w0 + m.y * w1 + m.z * w2 + m.w * w3;
        }
    }
#pragma unroll
    for (int r = 0; r < 8; r++) su[wv][r][j] = silu_f(acc[r]);
    __syncthreads();

    float acc2[8];
    float b2 = bn2[j];
#pragma unroll
    for (int r = 0; r < 8; r++) acc2[r] = sh[wv][r][j] + b2;
    for (int kb = 0; kb < 16; kb++) {
        float w0 = sW2[(4 * kb + 0) * 64 + j], w1 = sW2[(4 * kb + 1) * 64 + j];
        float w2 = sW2[(4 * kb + 2) * 64 + j], w3 = sW2[(4 * kb + 3) * 64 + j];
#pragma unroll
        for (int r = 0; r < 8; r++) {
            float4 m = *reinterpret_cast<const float4*>(&su[wv][r][4 * kb]);
            acc2[r] += m.x * w0 + m.y * w1 + m.z * w2 + m.w * w3;
        }
    }
#pragma unroll
    for (int r = 0; r < 8; r++) {
        int n = base + r;
        if (n < NN) h[n * 64 + j] = acc2[r];
    }
    if (j < 3) {
#pragma unroll
        for (int r = 0; r < 8; r++) {
            int n = base + r;
            if (n < NN) x[n * 3 + j] += dxb[n * 3 + j] * (1.f / 16.f);
        }
    }
}

// ---------------------------------------------------------------- latent bottleneck
__global__ __launch_bounds__(256) void k_latent(
    float* __restrict__ h, const float* __restrict__ Wl, const float* __restrict__ bl,
    const float* __restrict__ Wu, const float* __restrict__ bu)
{
    __shared__ float sWl[2048], sWu[2048];
    __shared__ __align__(16) float sh[4][8][64];
    __shared__ __align__(16) float sz[4][8][32];
    for (int i = threadIdx.x; i < 2048; i += 256) { sWl[i] = Wl[i]; sWu[i] = Wu[i]; }
    int wv = threadIdx.x >> 6, j = threadIdx.x & 63;
    int base = (blockIdx.x * 4 + wv) * 8;
#pragma unroll
    for (int r = 0; r < 8; r++) { int n = base + r; sh[wv][r][j] = (n < NN) ? h[n * 64 + j] : 0.f; }
    __syncthreads();
    if (j < 32) {
        float acc[8];
        float b0 = bl[j];
#pragma unroll
        for (int r = 0; r < 8; r++) acc[r] = b0;
        for (int kb = 0; kb < 16; kb++) {
            float w0 = sWl[(4 * kb + 0) * 32 + j], w1 = sWl[(4 * kb + 1) * 32 + j];
            float w2 = sWl[(4 * kb + 2) * 32 + j], w3 = sWl[(4 * kb + 3) * 32 + j];
#pragma unroll
            for (int r = 0; r < 8; r++) {
                float4 m = *reinterpret_cast<const float4*>(&sh[wv][r][4 * kb]);
                acc[r] += m.x * w0 + m.y * w1 + m.z * w2 + m.w * w3;
            }
        }
#pragma unroll
        for (int r = 0; r < 8; r++) sz[wv][r][j] = acc[r];
    }
    __syncthreads();
    float acc2[8];
    float b1 = bu[j];
#pragma unroll
    for (int r = 0; r < 8; r++) acc2[r] = b1;
    for (int kb = 0; kb < 8; kb++) {
        float w0 = sWu[(4 * kb + 0) * 64 + j], w1 = sWu[(4 * kb + 1) * 64 + j];
        float w2 = sWu[(4 * kb + 2) * 64 + j], w3 = sWu[(4 * kb + 3) * 64 + j];
#pragma unroll
        for (int r = 0; r < 8; r++) {
            float4 m = *reinterpret_cast<const float4*>(&sz[wv][r][4 * kb]);
            acc2[r] += m.x * w0 + m.y * w1 + m.z * w2 + m.w * w3;
        }
    }
#pragma unroll
    for (int r = 0; r < 8; r++) { int n = base + r; if (n < NN) h[n * 64 + j] = acc2[r]; }
}

// ---------------------------------------------------------------- output head
__global__ __launch_bounds__(256) void k_out(
    const float* __restrict__ h, const float* __restrict__ x,
    const float* __restrict__ Wo, const float* __restrict__ bo,
    float* __restrict__ out)
{
    int t = blockIdx.x * 256 + threadIdx.x;
    if (t >= NN * 19) return;
    int n = t / 19, c = t - n * 19;
    if (c < 16) {
        const float4* hr = reinterpret_cast<const float4*>(h + n * 64);
        float acc = bo[c];
#pragma unroll
        for (int kb = 0; kb < 16; kb++) {
            float4 hv = hr[kb];
            acc = fmaf(hv.x, Wo[(4 * kb + 0) * 16 + c], acc);
            acc = fmaf(hv.y, Wo[(4 * kb + 1) * 16 + c], acc);
            acc = fmaf(hv.z, Wo[(4 * kb + 2) * 16 + c], acc);
            acc = fmaf(hv.w, Wo[(4 * kb + 3) * 16 + c], acc);
        }
        out[t] = acc;
    } else {
        out[t] = x[n * 3 + (c - 16)];
    }
}

extern "C" void kernel_launch(void* const* d_in, const int* in_sizes, int n_in,
                              void* d_out, int out_size, void* d_ws, size_t ws_size,
                              hipStream_t stream)
{
    const float* h_in  = (const float*)d_in[0];
    const float* x_in  = (const float*)d_in[1];
    const int*   ei    = (const int*)d_in[2];
    const float* W_emb = (const float*)d_in[3];
    const float* b_emb = (const float*)d_in[4];
    const float* W_lat = (const float*)d_in[5];
    const float* b_lat = (const float*)d_in[6];
    const float* W_up  = (const float*)d_in[7];
    const float* b_up  = (const float*)d_in[8];
    const float* W_out = (const float*)d_in[9];
    const float* b_out = (const float*)d_in[10];
    const float* encp[9]; const float* decp[9];
    for (int i = 0; i < 9; i++) { encp[i] = (const float*)d_in[11 + i]; decp[i] = (const float*)d_in[20 + i]; }

    const int* src = ei;
    const int* dst = ei + NE;

    // workspace layout (floats): h[NN*64] x[NN*3] P[NN*64] Q[NN*64] agg[NN*64] dx[NN*3]  = 52.4 MB
    float* ws  = (float*)d_ws;
    float* h   = ws;
    float* xx  = h + NN * 64;
    float* P   = xx + NN * 3;
    float* Q   = P + NN * 64;
    float* agg = Q + NN * 64;
    float* dxb = agg + NN * 64;

    k_embed<<<(NN * 64) / 256, 256, 0, stream>>>(h_in, x_in, W_emb, b_emb, h, xx);

    for (int L = 0; L < 4; ++L) {
        const float** pp = (L < 2) ? encp : decp;
        int li = (L < 2) ? L : L - 2;
        const float* We1 = pp[0] + li * 129 * 64;
        const float* be1 = pp[1] + li * 64;
        const float* We2 = pp[2] + li * 64 * 64;
        const float* be2 = pp[3] + li * 64;
        const float* Wx  = pp[4] + li * 64;
        const float* Wn1 = pp[5] + li * 128 * 64;
        const float* bn1 = pp[6] + li * 64;
        const float* Wn2 = pp[7] + li * 64 * 64;
        const float* bn2 = pp[8] + li * 64;

        k_pq<<<(NN * 64) / 256, 256, 0, stream>>>(h, We1, be1, P, Q, agg, dxb);
        k_edge<<<NE / 32, 256, 0, stream>>>(src, dst, xx, P, Q, We1 + 128 * 64, We2, be2, Wx, agg, dxb);
        k_node<<<(NN + 31) / 32, 256, 0, stream>>>(h, xx, agg, dxb, Wn1, bn1, Wn2, bn2);
        if (L == 1) k_latent<<<(NN + 31) / 32, 256, 0, stream>>>(h, W_lat, b_lat, W_up, b_up);
    }

    k_out<<<(NN * 19 + 255) / 256, 256, 0, stream>>>(h, xx, W_out, b_out, (float*)d_out);
}